// Round 1
// baseline (278.649 us; speedup 1.0000x reference)
//
#include <hip/hip_runtime.h>
#include <stdint.h>

#define Bb 2
#define Tt 2048
#define Dd 1024
#define Hh 16
#define HDd 64
#define Mm 4096   // Bb*Tt

typedef __attribute__((ext_vector_type(4))) float f32x4;
typedef __attribute__((ext_vector_type(8))) __bf16 bf16x8;
typedef __attribute__((ext_vector_type(8))) short s16x8;
typedef __attribute__((ext_vector_type(4))) float fvec4;

__device__ __forceinline__ float bf2f(ushort u){
  union { unsigned int i; float f; } v; v.i = ((unsigned int)u) << 16; return v.f;
}
__device__ __forceinline__ ushort f2bf(float f){
  union { float f; unsigned int i; } v; v.f = f;
  unsigned int u = v.i;
  u += 0x7FFFu + ((u >> 16) & 1u);   // round-to-nearest-even
  return (ushort)(u >> 16);
}

__device__ __forceinline__ void gload16(const void* g, void* l){
  __builtin_amdgcn_global_load_lds(
      (const __attribute__((address_space(1))) void*)g,
      (__attribute__((address_space(3))) void*)l, 16, 0, 0);
}

// ---------------- fp32 -> bf16 convert ----------------
__global__ __launch_bounds__(256) void cvt_k(const float* __restrict__ in,
                                             ushort* __restrict__ out, int n4){
  int stride = gridDim.x * 256;
  for (int i = blockIdx.x * 256 + threadIdx.x; i < n4; i += stride){
    fvec4 v = ((const fvec4*)in)[i];
    unsigned int lo = (unsigned int)f2bf(v.x) | ((unsigned int)f2bf(v.y) << 16);
    unsigned int hi = (unsigned int)f2bf(v.z) | ((unsigned int)f2bf(v.w) << 16);
    ((uint2*)out)[i] = make_uint2(lo, hi);
  }
}

// ---------------- GEMM: out[m,n] = sum_k A[m,k]*W[n,k] + bias[n] ----------------
// 128x128 tile, BK=64, 4 waves, global_load_lds + XOR-swizzled LDS.
template<bool OUTF32>
__device__ __forceinline__ void gemm_body(
    const ushort* __restrict__ A, const ushort* __restrict__ W,
    const float* __restrict__ bias, ushort* __restrict__ Oh, float* __restrict__ Of,
    int m0, int n0, int N, int K)
{
  __shared__ ushort As[128*64];
  __shared__ ushort Bs[128*64];
  const int tid  = threadIdx.x;
  const int w    = tid >> 6, lid = tid & 63;
  const int lrow = lid & 15, g = lid >> 4;
  const int wm   = (w >> 1) << 6, wn = (w & 1) << 6;

  f32x4 acc[4][4] = {};

  for (int kt = 0; kt < K; kt += 64){
    __syncthreads();
    #pragma unroll
    for (int i = 0; i < 4; ++i){
      int e   = tid + i*256;
      int row = e >> 3;
      int c   = (e & 7) ^ (row & 7);   // pre-swizzle global source (linear LDS dest)
      gload16(A + (size_t)(m0 + row)*K + kt + c*8, &As[e*8]);
      gload16(W + (size_t)(n0 + row)*K + kt + c*8, &Bs[e*8]);
    }
    __syncthreads();
    #pragma unroll
    for (int kc = 0; kc < 2; ++kc){
      bf16x8 af[4], bfr[4];
      #pragma unroll
      for (int r = 0; r < 4; ++r){
        int row = wm + r*16 + lrow;
        af[r] = *(const bf16x8*)&As[row*64 + (((kc*4 + g) ^ (row & 7)) << 3)];
      }
      #pragma unroll
      for (int c = 0; c < 4; ++c){
        int row = wn + c*16 + lrow;
        bfr[c] = *(const bf16x8*)&Bs[row*64 + (((kc*4 + g) ^ (row & 7)) << 3)];
      }
      #pragma unroll
      for (int r = 0; r < 4; ++r)
        #pragma unroll
        for (int c = 0; c < 4; ++c)
          acc[r][c] = __builtin_amdgcn_mfma_f32_16x16x32_bf16(af[r], bfr[c], acc[r][c], 0, 0, 0);
    }
  }
  // epilogue: D row=(lane>>4)*4+b, col=lane&15
  #pragma unroll
  for (int r = 0; r < 4; ++r){
    #pragma unroll
    for (int c = 0; c < 4; ++c){
      #pragma unroll
      for (int b = 0; b < 4; ++b){
        int row = m0 + wm + r*16 + g*4 + b;
        int col = n0 + wn + c*16 + lrow;
        float v = acc[r][c][b] + bias[col];
        if (OUTF32) Of[(size_t)row*N + col] = v;
        else        Oh[(size_t)row*N + col] = f2bf(v);
      }
    }
  }
}

__global__ __launch_bounds__(256) void gemm_qkv(
  const ushort* __restrict__ qbf, const ushort* __restrict__ kvbf,
  const ushort* __restrict__ wq, const ushort* __restrict__ wk, const ushort* __restrict__ wv,
  const float* __restrict__ bq, const float* __restrict__ bk, const float* __restrict__ bv,
  ushort* __restrict__ Q, ushort* __restrict__ Kx, ushort* __restrict__ V)
{
  int bid = blockIdx.x;
  int mt  = bid / 24;
  int ntg = bid % 24;
  int proj = ntg >> 3, nt = ntg & 7;
  const ushort* A   = proj ? kvbf : qbf;
  const ushort* W   = (proj == 0) ? wq : (proj == 1 ? wk : wv);
  const float*  bia = (proj == 0) ? bq : (proj == 1 ? bk : bv);
  ushort*       O   = (proj == 0) ? Q  : (proj == 1 ? Kx : V);
  gemm_body<false>(A, W, bia, O, nullptr, mt*128, nt*128, Dd, Dd);
}

__global__ __launch_bounds__(256) void gemm_o(
  const ushort* __restrict__ X, const ushort* __restrict__ wo,
  const float* __restrict__ bo, float* __restrict__ out)
{
  int bid = blockIdx.x;
  int mt = bid / 8, nt = bid % 8;
  gemm_body<true>(X, wo, bo, nullptr, out, mt*128, nt*128, Dd, Dd);
}

// ---------------- per-head RMSNorm (in-place on bf16, groups of 64 contiguous) ----------------
__global__ __launch_bounds__(256) void rmsnorm_k(ushort* __restrict__ x, const float* __restrict__ w){
  int wid  = (blockIdx.x * 256 + threadIdx.x) >> 6;
  int lane = threadIdx.x & 63;
  ushort* p = x + (size_t)wid * 64;
  float v = bf2f(p[lane]);
  float s = v * v;
  #pragma unroll
  for (int m = 32; m >= 1; m >>= 1) s += __shfl_xor(s, m, 64);
  float r = rsqrtf(s * (1.0f/64.0f) + 1e-6f);
  p[lane] = f2bf(v * r * w[lane]);
}

// ---------------- flash attention ----------------
// grid = 32 qt * 32 bh ; block = 256 (4 waves x 16 q-rows) ; KBLK=64
__global__ __launch_bounds__(256) void attn_k(
  const ushort* __restrict__ Qb, const ushort* __restrict__ Kb,
  const ushort* __restrict__ Vb, ushort* __restrict__ Ob)
{
  __shared__ ushort Ks[64*64];      // K tile, row=key, XOR-swizzled chunks
  __shared__ ushort Vt[64*64];      // V^T tile, row=d, col=key, swizzled
  __shared__ ushort Ps[4][16*64];   // per-wave P buffer, row=q, col=key, swizzled

  const int tid  = threadIdx.x;
  const int w    = tid >> 6, lid = tid & 63;
  const int lrow = lid & 15, g = lid >> 4;

  const int bid = blockIdx.x;
  const int bh  = bid & 31;
  const int qt  = bid >> 5;
  const int bb  = bh >> 4, h = bh & 15;

  const size_t base = (size_t)bb * Tt * Dd + (size_t)h * HDd;

  const int qrow = qt*64 + w*16 + lrow;
  bf16x8 qf[2];
  #pragma unroll
  for (int kc = 0; kc < 2; ++kc)
    qf[kc] = *(const bf16x8*)&Qb[base + (size_t)qrow*Dd + kc*32 + g*8];

  f32x4 o[4] = {};
  float mr[4] = {-1e30f,-1e30f,-1e30f,-1e30f};
  float lr[4] = {0.f,0.f,0.f,0.f};

  ushort* Pw = Ps[w];

  for (int kt = 0; kt < 32; ++kt){
    __syncthreads();
    // ---- stage K (row-major swizzled) and V^T (transposed scatter, swizzled)
    #pragma unroll
    for (int i = 0; i < 2; ++i){
      int e  = tid + i*256;          // 0..511
      int kr = e >> 3;               // key row 0..63
      int c8 = (e & 7) << 3;         // d-chunk base
      const ushort* gk = Kb + base + (size_t)(kt*64 + kr)*Dd + c8;
      *(s16x8*)&Ks[kr*64 + (((e & 7) ^ (kr & 7)) << 3)] = *(const s16x8*)gk;
      s16x8 vv = *(const s16x8*)(Vb + base + (size_t)(kt*64 + kr)*Dd + c8);
      #pragma unroll
      for (int j = 0; j < 8; ++j){
        int d = c8 + j;
        Vt[d*64 + (((kr >> 3) ^ (d & 7)) << 3) + (kr & 7)] = (ushort)vv[j];
      }
    }
    __syncthreads();

    // ---- S = Q K^T  (per wave: 16 q x 64 keys)
    f32x4 s[4] = {};
    #pragma unroll
    for (int t = 0; t < 4; ++t){
      #pragma unroll
      for (int kc = 0; kc < 2; ++kc){
        int row = t*16 + lrow;
        bf16x8 kf = *(const bf16x8*)&Ks[row*64 + ((((kc*4 + g) ^ (row & 7))) << 3)];
        s[t] = __builtin_amdgcn_mfma_f32_16x16x32_bf16(qf[kc], kf, s[t], 0, 0, 0);
      }
    }
    #pragma unroll
    for (int t = 0; t < 4; ++t) s[t] *= 0.125f;   // HD^-0.5

    // ---- online softmax; lane holds rows q = g*4+b, col = lane&15 (+16t)
    float mx[4];
    #pragma unroll
    for (int q = 0; q < 4; ++q)
      mx[q] = fmaxf(fmaxf(s[0][q], s[1][q]), fmaxf(s[2][q], s[3][q]));
    #pragma unroll
    for (int msk = 1; msk <= 8; msk <<= 1){
      #pragma unroll
      for (int q = 0; q < 4; ++q)
        mx[q] = fmaxf(mx[q], __shfl_xor(mx[q], msk, 64));
    }

    float pr[4][4];
    float rs[4];
    #pragma unroll
    for (int q = 0; q < 4; ++q){
      float nm = fmaxf(mr[q], mx[q]);
      float f  = exp2f((mr[q] - nm) * 1.44269504f);
      mr[q] = nm;
      lr[q] *= f;
      #pragma unroll
      for (int t = 0; t < 4; ++t) o[t][q] *= f;
      float a = 0.f;
      #pragma unroll
      for (int t = 0; t < 4; ++t){
        float p = exp2f((s[t][q] - nm) * 1.44269504f);
        pr[t][q] = p;
        a += p;
      }
      rs[q] = a;
    }
    #pragma unroll
    for (int msk = 1; msk <= 8; msk <<= 1){
      #pragma unroll
      for (int q = 0; q < 4; ++q)
        rs[q] += __shfl_xor(rs[q], msk, 64);
    }
    #pragma unroll
    for (int q = 0; q < 4; ++q) lr[q] += rs[q];

    // ---- P -> per-wave LDS (D-layout -> A-layout round trip)
    #pragma unroll
    for (int q = 0; q < 4; ++q){
      int qr = g*4 + q;
      #pragma unroll
      for (int t = 0; t < 4; ++t){
        int key = t*16 + lrow;
        Pw[qr*64 + ((((key >> 3) ^ (qr & 7))) << 3) + (key & 7)] = f2bf(pr[t][q]);
      }
    }
    asm volatile("s_waitcnt lgkmcnt(0)" ::: "memory");

    // ---- O += P V
    #pragma unroll
    for (int kc = 0; kc < 2; ++kc){
      bf16x8 pa = *(const bf16x8*)&Pw[lrow*64 + ((((kc*4 + g) ^ (lrow & 7))) << 3)];
      #pragma unroll
      for (int t = 0; t < 4; ++t){
        int d = t*16 + lrow;
        bf16x8 vf = *(const bf16x8*)&Vt[d*64 + ((((kc*4 + g) ^ (d & 7))) << 3)];
        o[t] = __builtin_amdgcn_mfma_f32_16x16x32_bf16(pa, vf, o[t], 0, 0, 0);
      }
    }
  }

  // ---- finalize: O /= l, write bf16 into [B,T,D] layout
  #pragma unroll
  for (int q = 0; q < 4; ++q){
    float inv = 1.0f / lr[q];
    int row = qt*64 + w*16 + g*4 + q;
    #pragma unroll
    for (int t = 0; t < 4; ++t){
      Ob[base + (size_t)row*Dd + t*16 + lrow] = f2bf(o[t][q] * inv);
    }
  }
}

extern "C" void kernel_launch(void* const* d_in, const int* in_sizes, int n_in,
                              void* d_out, int out_size, void* d_ws, size_t ws_size,
                              hipStream_t stream)
{
  const float* query = (const float*)d_in[0];
  const float* keyv  = (const float*)d_in[1];
  const float* Wq    = (const float*)d_in[2];
  const float* bq    = (const float*)d_in[3];
  const float* Wk    = (const float*)d_in[4];
  const float* bk    = (const float*)d_in[5];
  const float* Wv    = (const float*)d_in[6];
  const float* bv    = (const float*)d_in[7];
  const float* Wo    = (const float*)d_in[8];
  const float* bo    = (const float*)d_in[9];
  const float* qnw   = (const float*)d_in[10];
  const float* knw   = (const float*)d_in[11];
  float* out = (float*)d_out;

  char* p = (char*)d_ws;
  ushort* qbf  = (ushort*)p; p += (size_t)Mm*Dd*2;
  ushort* kvbf = (ushort*)p; p += (size_t)Mm*Dd*2;
  ushort* wqb  = (ushort*)p; p += (size_t)Dd*Dd*2;
  ushort* wkb  = (ushort*)p; p += (size_t)Dd*Dd*2;
  ushort* wvb  = (ushort*)p; p += (size_t)Dd*Dd*2;
  ushort* wob  = (ushort*)p; p += (size_t)Dd*Dd*2;
  ushort* Qb   = (ushort*)p; p += (size_t)Mm*Dd*2;
  ushort* Kbf  = (ushort*)p; p += (size_t)Mm*Dd*2;
  ushort* Vbf  = (ushort*)p; p += (size_t)Mm*Dd*2;
  ushort* Ab   = (ushort*)p; p += (size_t)Mm*Dd*2;

  cvt_k<<<dim3(1024), dim3(256), 0, stream>>>(query, qbf, Mm*Dd/4);
  cvt_k<<<dim3(1024), dim3(256), 0, stream>>>(keyv, kvbf, Mm*Dd/4);
  cvt_k<<<dim3(512),  dim3(256), 0, stream>>>(Wq, wqb, Dd*Dd/4);
  cvt_k<<<dim3(512),  dim3(256), 0, stream>>>(Wk, wkb, Dd*Dd/4);
  cvt_k<<<dim3(512),  dim3(256), 0, stream>>>(Wv, wvb, Dd*Dd/4);
  cvt_k<<<dim3(512),  dim3(256), 0, stream>>>(Wo, wob, Dd*Dd/4);

  gemm_qkv<<<dim3(768), dim3(256), 0, stream>>>(qbf, kvbf, wqb, wkb, wvb,
                                                bq, bk, bv, Qb, Kbf, Vbf);

  rmsnorm_k<<<dim3(16384), dim3(256), 0, stream>>>(Qb,  qnw);
  rmsnorm_k<<<dim3(16384), dim3(256), 0, stream>>>(Kbf, knw);

  attn_k<<<dim3(1024), dim3(256), 0, stream>>>(Qb, Kbf, Vbf, Ab);

  gemm_o<<<dim3(256), dim3(256), 0, stream>>>(Ab, wob, bo, out);
}

// Round 3
// 164.058 us; speedup vs baseline: 1.6985x; 1.6985x over previous
//
#include <hip/hip_runtime.h>
#include <stdint.h>

#define Bb 2
#define Tt 2048
#define Dd 1024
#define Hh 16
#define HDd 64
#define Mm 4096   // Bb*Tt

typedef __attribute__((ext_vector_type(4))) float f32x4;
typedef __attribute__((ext_vector_type(8))) __bf16 bf16x8;
typedef __attribute__((ext_vector_type(8))) short s16x8;
typedef __attribute__((ext_vector_type(4))) short s16x4;
typedef __attribute__((ext_vector_type(4))) float fvec4;

__device__ __forceinline__ float bf2f(ushort u){
  union { unsigned int i; float f; } v; v.i = ((unsigned int)u) << 16; return v.f;
}
__device__ __forceinline__ ushort f2bf(float f){
  union { float f; unsigned int i; } v; v.f = f;
  unsigned int u = v.i;
  u += 0x7FFFu + ((u >> 16) & 1u);   // round-to-nearest-even
  return (ushort)(u >> 16);
}

__device__ __forceinline__ void gload16(const void* g, void* l){
  __builtin_amdgcn_global_load_lds(
      (const __attribute__((address_space(1))) void*)g,
      (__attribute__((address_space(3))) void*)l, 16, 0, 0);
}

__device__ __forceinline__ bf16x8 cat4(s16x4 a, s16x4 b){
  s16x8 c = __builtin_shufflevector(a, b, 0,1,2,3,4,5,6,7);
  return __builtin_bit_cast(bf16x8, c);
}

// ---------------- fused fp32 -> bf16 convert (all 6 tensors, one launch) ----------------
__global__ __launch_bounds__(256) void cvt_all(
    const float* __restrict__ q, const float* __restrict__ kv,
    const float* __restrict__ wq, const float* __restrict__ wk,
    const float* __restrict__ wv, const float* __restrict__ wo,
    ushort* __restrict__ oq, ushort* __restrict__ okv, ushort* __restrict__ owq,
    ushort* __restrict__ owk, ushort* __restrict__ owv, ushort* __restrict__ owo)
{
  const int NQ = Mm*Dd/4;     // 1048576 vec4
  const int NW = Dd*Dd/4;     // 262144 vec4
  int j = blockIdx.x * 256 + threadIdx.x;   // grid covers 2*NQ+4*NW exactly
  const float* s; ushort* d;
  if (j < NQ)            { s = q;  d = oq;  }
  else if ((j -= NQ) < NQ){ s = kv; d = okv; }
  else if ((j -= NQ) < NW){ s = wq; d = owq; }
  else if ((j -= NW) < NW){ s = wk; d = owk; }
  else if ((j -= NW) < NW){ s = wv; d = owv; }
  else        { j -= NW;   s = wo; d = owo; }
  fvec4 v = ((const fvec4*)s)[j];
  unsigned int lo = (unsigned int)f2bf(v.x) | ((unsigned int)f2bf(v.y) << 16);
  unsigned int hi = (unsigned int)f2bf(v.z) | ((unsigned int)f2bf(v.w) << 16);
  ((uint2*)d)[j] = make_uint2(lo, hi);
}

// ---------------- GEMM: out[m,n] = sum_k A[m,k]*W[n,k] + bias[n] ----------------
// MODE 0: bf16 out.  MODE 1: bf16 out + per-64-col RMSNorm (*rmsScale).  MODE 2: f32 out.
template<int MODE>
__device__ __forceinline__ void gemm_body(
    const ushort* __restrict__ A, const ushort* __restrict__ W,
    const float* __restrict__ bias, ushort* __restrict__ Oh, float* __restrict__ Of,
    const float* __restrict__ nw, float rmsScale,
    int m0, int n0, int N, int K)
{
  __shared__ ushort As[128*64];
  __shared__ ushort Bs[128*64];
  const int tid  = threadIdx.x;
  const int w    = tid >> 6, lid = tid & 63;
  const int lrow = lid & 15, g = lid >> 4;
  const int wm   = (w >> 1) << 6, wn = (w & 1) << 6;

  f32x4 acc[4][4] = {};

  for (int kt = 0; kt < K; kt += 64){
    __syncthreads();
    #pragma unroll
    for (int i = 0; i < 4; ++i){
      int e   = tid + i*256;
      int row = e >> 3;
      int c   = (e & 7) ^ (row & 7);   // pre-swizzle global source (linear LDS dest)
      gload16(A + (size_t)(m0 + row)*K + kt + c*8, &As[e*8]);
      gload16(W + (size_t)(n0 + row)*K + kt + c*8, &Bs[e*8]);
    }
    __syncthreads();
    #pragma unroll
    for (int kc = 0; kc < 2; ++kc){
      bf16x8 af[4], bfr[4];
      #pragma unroll
      for (int r = 0; r < 4; ++r){
        int row = wm + r*16 + lrow;
        af[r] = *(const bf16x8*)&As[row*64 + (((kc*4 + g) ^ (row & 7)) << 3)];
      }
      #pragma unroll
      for (int c = 0; c < 4; ++c){
        int row = wn + c*16 + lrow;
        bfr[c] = *(const bf16x8*)&Bs[row*64 + (((kc*4 + g) ^ (row & 7)) << 3)];
      }
      #pragma unroll
      for (int r = 0; r < 4; ++r)
        #pragma unroll
        for (int c = 0; c < 4; ++c)
          acc[r][c] = __builtin_amdgcn_mfma_f32_16x16x32_bf16(af[r], bfr[c], acc[r][c], 0, 0, 0);
    }
  }
  // epilogue: D row=(lane>>4)*4+b, col=lane&15
  const int colbase = n0 + wn;
  float bv[4], wv4[4];
  #pragma unroll
  for (int c = 0; c < 4; ++c){
    bv[c] = bias[colbase + c*16 + lrow];
    if (MODE == 1) wv4[c] = nw[c*16 + lrow];   // head dim = col % 64 = c*16+lrow
  }
  #pragma unroll
  for (int r = 0; r < 4; ++r){
    #pragma unroll
    for (int b = 0; b < 4; ++b){
      float v[4];
      #pragma unroll
      for (int c = 0; c < 4; ++c) v[c] = acc[r][c][b] + bv[c];
      float sc = 1.0f;
      if (MODE == 1){
        // wave's 64 cols (c,lrow) = exactly one 64-dim head group
        float ss = v[0]*v[0] + v[1]*v[1] + v[2]*v[2] + v[3]*v[3];
        ss += __shfl_xor(ss, 1, 64);
        ss += __shfl_xor(ss, 2, 64);
        ss += __shfl_xor(ss, 4, 64);
        ss += __shfl_xor(ss, 8, 64);
        sc = rsqrtf(ss * (1.0f/64.0f) + 1e-6f) * rmsScale;
      }
      int row = m0 + wm + r*16 + g*4 + b;
      #pragma unroll
      for (int c = 0; c < 4; ++c){
        int col = colbase + c*16 + lrow;
        if (MODE == 2)      Of[(size_t)row*N + col] = v[c];
        else if (MODE == 1) Oh[(size_t)row*N + col] = f2bf(v[c] * sc * wv4[c]);
        else                Oh[(size_t)row*N + col] = f2bf(v[c]);
      }
    }
  }
}

__global__ __launch_bounds__(256) void gemm_qkv(
  const ushort* __restrict__ qbf, const ushort* __restrict__ kvbf,
  const ushort* __restrict__ wq, const ushort* __restrict__ wk, const ushort* __restrict__ wv,
  const float* __restrict__ bq, const float* __restrict__ bk, const float* __restrict__ bv,
  const float* __restrict__ qnw, const float* __restrict__ knw,
  ushort* __restrict__ Q, ushort* __restrict__ Kx, ushort* __restrict__ V)
{
  int bid = blockIdx.x;
  int mt  = bid / 24;
  int ntg = bid % 24;
  int proj = ntg >> 3, nt = ntg & 7;
  // Q gets rmsnorm * (0.125 * log2e)  -> softmax scale folded in; exp2 used directly
  if (proj == 0)
    gemm_body<1>(qbf, wq, bq, Q, nullptr, qnw, 0.18033688011112042f, mt*128, nt*128, Dd, Dd);
  else if (proj == 1)
    gemm_body<1>(kvbf, wk, bk, Kx, nullptr, knw, 1.0f, mt*128, nt*128, Dd, Dd);
  else
    gemm_body<0>(kvbf, wv, bv, V, nullptr, nullptr, 1.0f, mt*128, nt*128, Dd, Dd);
}

__global__ __launch_bounds__(256) void gemm_o(
  const ushort* __restrict__ X, const ushort* __restrict__ wo,
  const float* __restrict__ bo, float* __restrict__ out)
{
  int bid = blockIdx.x;
  int mt = bid / 8, nt = bid % 8;
  gemm_body<2>(X, wo, bo, nullptr, out, nullptr, 1.0f, mt*128, nt*128, Dd, Dd);
}

// ---------------- flash attention, swapped-QK^T, O^T-orientation PV ----------------
// grid = 16 qt * 32 bh (XCD-swizzled); block = 256 = 4 waves; wave owns 32 q (2 subtiles)
// KBLK = 64. K double-buffered via global_load_lds; V reg-staged then scatter-written
// as V^T into LDS with an element-bijective swizzle (write ~2-way, read contiguous).
__global__ __launch_bounds__(256, 2) void attn_k(
  const ushort* __restrict__ Qb, const ushort* __restrict__ Kb,
  const ushort* __restrict__ Vb, ushort* __restrict__ Ob)
{
  __shared__ ushort Ks[2][64*64];   // [key][d], chunk-XOR-swizzled rows (verified pattern)
  __shared__ ushort Vt[2][64*64];   // V^T: element (d,key) at d*64 + ((key>>3 ^ F(d))<<3) + (key&7)

  const int tid = threadIdx.x;
  const int w   = tid >> 6, lid = tid & 63;
  const int r   = lid & 15, g = lid >> 4;

  int bid = blockIdx.x;
  int wg  = (bid & 7) * 64 + (bid >> 3);   // 512 blocks -> 8 XCD contiguous chunks
  int bh  = wg >> 4, qt = wg & 15;
  int bb  = bh >> 4, h = bh & 15;
  const size_t base = (size_t)bb * Tt * Dd + (size_t)h * HDd;

  // Q fragments (B-operand of QK^T): lane holds Q[q=qt*128+w*32+sub*16+r][kc*32+g*8..]
  bf16x8 qf[2][2];
  #pragma unroll
  for (int sub = 0; sub < 2; ++sub)
    #pragma unroll
    for (int kc = 0; kc < 2; ++kc)
      qf[sub][kc] = *(const bf16x8*)&Qb[base + (size_t)(qt*128 + w*32 + sub*16 + r)*Dd + kc*32 + g*8];

  // staging source pointers
  const ushort* ksrc[2];
  const ushort* vsrc[2];
  #pragma unroll
  for (int i = 0; i < 2; ++i){
    int e = tid + i*256;
    int row = e >> 3, c = (e & 7) ^ (row & 7);
    ksrc[i] = Kb + base + (size_t)row * Dd + c*8;              // pre-swizzled for gload16
    vsrc[i] = Vb + base + (size_t)(e >> 3) * Dd + (e & 7)*8;   // plain rows for reg-stage
  }
  const size_t kstep = (size_t)64 * Dd;

  // prologue: K tile0 -> Ks[0] via DMA; V tile0 -> regs
  #pragma unroll
  for (int i = 0; i < 2; ++i)
    gload16(ksrc[i], &Ks[0][(tid + i*256)*8]);
  s16x8 vreg[2];
  #pragma unroll
  for (int i = 0; i < 2; ++i)
    vreg[i] = *(const s16x8*)vsrc[i];

  f32x4 o[2][4] = {};          // o[sub][t16]: O[q=r][d = t16*16 + g*4 + b]
  float mr[2] = {-1e30f, -1e30f};
  float lr[2] = {0.f, 0.f};

  for (int kt = 0; kt < 32; ++kt){
    const int cur = kt & 1;

    // ---- scatter-write this tile's V^T into Vt[cur] (element-bijective swizzle)
    {
      ushort* vd = Vt[cur];
      #pragma unroll
      for (int i = 0; i < 2; ++i){
        int e = tid + i*256;
        int kr = e >> 3, c8 = (e & 7) << 3;
        #pragma unroll
        for (int j = 0; j < 8; ++j){
          int d = c8 + j;
          int F = ((d >> 3) ^ d) & 7;
          vd[d*64 + (((kr >> 3) ^ F) << 3) + (kr & 7)] = (ushort)vreg[i][j];
        }
      }
    }
    __syncthreads();   // drains vmcnt (K DMA for cur) + lgkm (V^T writes); all waves aligned

    // ---- prefetch next tile: K via DMA into other buffer, V into regs (overlaps compute)
    if (kt + 1 < 32){
      const size_t adv = (size_t)(kt + 1) * kstep;
      #pragma unroll
      for (int i = 0; i < 2; ++i)
        gload16(ksrc[i] + adv, &Ks[cur^1][(tid + i*256)*8]);
      #pragma unroll
      for (int i = 0; i < 2; ++i)
        vreg[i] = *(const s16x8*)(vsrc[i] + adv);
    }

    // ---- swapped QK^T: S^T = mfma(K, Q); lane holds S[key = 16t+4g+b][q = r]
    f32x4 s0[4] = {}, s1[4] = {};
    const ushort* kb = Ks[cur];
    #pragma unroll
    for (int kc = 0; kc < 2; ++kc)
      #pragma unroll
      for (int t = 0; t < 4; ++t){
        int row = t*16 + r;
        bf16x8 kf = *(const bf16x8*)&kb[row*64 + (((kc*4 + g) ^ (row & 7)) << 3)];
        s0[t] = __builtin_amdgcn_mfma_f32_16x16x32_bf16(kf, qf[0][kc], s0[t], 0, 0, 0);
        s1[t] = __builtin_amdgcn_mfma_f32_16x16x32_bf16(kf, qf[1][kc], s1[t], 0, 0, 0);
      }

    // ---- online softmax (scale pre-folded into Q as 0.125*log2e -> exp2 direct)
    bf16x8 pa[2][2];
    auto dosm = [&](const f32x4* s, float& m, float& l, bf16x8* pao) -> float {
      float mx = s[0][0];
      #pragma unroll
      for (int t = 0; t < 4; ++t)
        #pragma unroll
        for (int b = 0; b < 4; ++b) mx = fmaxf(mx, s[t][b]);
      mx = fmaxf(mx, __shfl_xor(mx, 16, 64));
      mx = fmaxf(mx, __shfl_xor(mx, 32, 64));
      float nm = fmaxf(m, mx);
      float f = exp2f(m - nm);
      float p[4][4]; float rs = 0.f;
      #pragma unroll
      for (int t = 0; t < 4; ++t)
        #pragma unroll
        for (int b = 0; b < 4; ++b){ float e = exp2f(s[t][b] - nm); p[t][b] = e; rs += e; }
      rs += __shfl_xor(rs, 16, 64);
      rs += __shfl_xor(rs, 32, 64);
      l = l * f + rs;
      m = nm;
      // pack P as PV B-operand: slot j of pao[kc] = P[q=r][key = 16*(2kc+(j>>2)) + 4g + (j&3)]
      #pragma unroll
      for (int kc = 0; kc < 2; ++kc){
        bf16x8 v;
        #pragma unroll
        for (int j = 0; j < 8; ++j) v[j] = (__bf16)p[(j >> 2) + 2*kc][j & 3];
        pao[kc] = v;
      }
      return f;
    };
    float f0 = dosm(s0, mr[0], lr[0], pa[0]);
    float f1 = dosm(s1, mr[1], lr[1], pa[1]);

    // rescale O (q = r is lane-local -> no shuffles)
    #pragma unroll
    for (int t16 = 0; t16 < 4; ++t16){ o[0][t16] *= f0; o[1][t16] *= f1; }

    // ---- PV (O^T orientation): o = mfma(A = V^T frag, B = P frag)
    const ushort* vb = Vt[cur];
    #pragma unroll
    for (int t16 = 0; t16 < 4; ++t16){
      int d = t16*16 + r;
      int F = ((d >> 3) ^ d) & 7;
      const ushort* vrow = &vb[d*64 + 4*(g & 1)];
      #pragma unroll
      for (int kc = 0; kc < 2; ++kc){
        int c0 = 4*kc + (g >> 1);
        s16x4 v0 = *(const s16x4*)&vrow[(c0 ^ F) << 3];          // keys 32kc+4g+0..3
        s16x4 v1 = *(const s16x4*)&vrow[((c0 + 2) ^ F) << 3];    // keys 32kc+16+4g+0..3
        bf16x8 vf = cat4(v0, v1);
        o[0][t16] = __builtin_amdgcn_mfma_f32_16x16x32_bf16(vf, pa[0][kc], o[0][t16], 0, 0, 0);
        o[1][t16] = __builtin_amdgcn_mfma_f32_16x16x32_bf16(vf, pa[1][kc], o[1][t16], 0, 0, 0);
      }
    }
  }

  // ---- finalize: O /= l (lane-local), write 4 contiguous bf16 (8B) per t16
  #pragma unroll
  for (int sub = 0; sub < 2; ++sub){
    float inv = 1.0f / lr[sub];
    int qrow = qt*128 + w*32 + sub*16 + r;
    #pragma unroll
    for (int t16 = 0; t16 < 4; ++t16){
      uint2 u;
      u.x = (unsigned)f2bf(o[sub][t16][0]*inv) | ((unsigned)f2bf(o[sub][t16][1]*inv) << 16);
      u.y = (unsigned)f2bf(o[sub][t16][2]*inv) | ((unsigned)f2bf(o[sub][t16][3]*inv) << 16);
      *(uint2*)&Ob[base + (size_t)qrow*Dd + t16*16 + g*4] = u;
    }
  }
}

extern "C" void kernel_launch(void* const* d_in, const int* in_sizes, int n_in,
                              void* d_out, int out_size, void* d_ws, size_t ws_size,
                              hipStream_t stream)
{
  const float* query = (const float*)d_in[0];
  const float* keyv  = (const float*)d_in[1];
  const float* Wq    = (const float*)d_in[2];
  const float* bq    = (const float*)d_in[3];
  const float* Wk    = (const float*)d_in[4];
  const float* bk    = (const float*)d_in[5];
  const float* Wv    = (const float*)d_in[6];
  const float* bv    = (const float*)d_in[7];
  const float* Wo    = (const float*)d_in[8];
  const float* bo    = (const float*)d_in[9];
  const float* qnw   = (const float*)d_in[10];
  const float* knw   = (const float*)d_in[11];
  float* out = (float*)d_out;

  char* p = (char*)d_ws;
  ushort* qbf  = (ushort*)p; p += (size_t)Mm*Dd*2;
  ushort* kvbf = (ushort*)p; p += (size_t)Mm*Dd*2;
  ushort* wqb  = (ushort*)p; p += (size_t)Dd*Dd*2;
  ushort* wkb  = (ushort*)p; p += (size_t)Dd*Dd*2;
  ushort* wvb  = (ushort*)p; p += (size_t)Dd*Dd*2;
  ushort* wob  = (ushort*)p; p += (size_t)Dd*Dd*2;
  ushort* Qb   = (ushort*)p; p += (size_t)Mm*Dd*2;
  ushort* Kbf  = (ushort*)p; p += (size_t)Mm*Dd*2;
  ushort* Vbf  = (ushort*)p; p += (size_t)Mm*Dd*2;
  ushort* Ab   = (ushort*)p; p += (size_t)Mm*Dd*2;

  cvt_all<<<dim3(12288), dim3(256), 0, stream>>>(query, keyv, Wq, Wk, Wv, Wo,
                                                 qbf, kvbf, wqb, wkb, wvb, wob);

  gemm_qkv<<<dim3(768), dim3(256), 0, stream>>>(qbf, kvbf, wqb, wkb, wvb,
                                                bq, bk, bv, qnw, knw, Qb, Kbf, Vbf);

  attn_k<<<dim3(512), dim3(256), 0, stream>>>(Qb, Kbf, Vbf, Ab);

  gemm_o<<<dim3(256), dim3(256), 0, stream>>>(Ab, wob, bo, out);
}

// Round 4
// 141.351 us; speedup vs baseline: 1.9713x; 1.1606x over previous
//
#include <hip/hip_runtime.h>
#include <stdint.h>

#define Bb 2
#define Tt 2048
#define Dd 1024
#define Hh 16
#define HDd 64
#define Mm 4096   // Bb*Tt

typedef __attribute__((ext_vector_type(4))) float f32x4;
typedef __attribute__((ext_vector_type(8))) __bf16 bf16x8;
typedef __attribute__((ext_vector_type(8))) short s16x8;
typedef __attribute__((ext_vector_type(4))) short s16x4;
typedef __attribute__((ext_vector_type(4))) float fvec4;
typedef __attribute__((ext_vector_type(4))) unsigned int u32x4;

__device__ __forceinline__ float bf2f(ushort u){
  union { unsigned int i; float f; } v; v.i = ((unsigned int)u) << 16; return v.f;
}
__device__ __forceinline__ ushort f2bf(float f){
  union { float f; unsigned int i; } v; v.f = f;
  unsigned int u = v.i;
  u += 0x7FFFu + ((u >> 16) & 1u);   // round-to-nearest-even
  return (ushort)(u >> 16);
}

__device__ __forceinline__ void gload16(const void* g, void* l){
  __builtin_amdgcn_global_load_lds(
      (const __attribute__((address_space(1))) void*)g,
      (__attribute__((address_space(3))) void*)l, 16, 0, 0);
}

__device__ __forceinline__ bf16x8 cat4(s16x4 a, s16x4 b){
  s16x8 c = __builtin_shufflevector(a, b, 0,1,2,3,4,5,6,7);
  return __builtin_bit_cast(bf16x8, c);
}

// ---------------- fused fp32 -> bf16 convert (all 6 tensors, one launch) ----------------
__global__ __launch_bounds__(256) void cvt_all(
    const float* __restrict__ q, const float* __restrict__ kv,
    const float* __restrict__ wq, const float* __restrict__ wk,
    const float* __restrict__ wv, const float* __restrict__ wo,
    ushort* __restrict__ oq, ushort* __restrict__ okv, ushort* __restrict__ owq,
    ushort* __restrict__ owk, ushort* __restrict__ owv, ushort* __restrict__ owo)
{
  const int NQ = Mm*Dd/4;     // 1048576 vec4
  const int NW = Dd*Dd/4;     // 262144 vec4
  int j = blockIdx.x * 256 + threadIdx.x;   // grid covers 2*NQ+4*NW exactly
  const float* s; ushort* d;
  if (j < NQ)            { s = q;  d = oq;  }
  else if ((j -= NQ) < NQ){ s = kv; d = okv; }
  else if ((j -= NQ) < NW){ s = wq; d = owq; }
  else if ((j -= NW) < NW){ s = wk; d = owk; }
  else if ((j -= NW) < NW){ s = wv; d = owv; }
  else        { j -= NW;   s = wo; d = owo; }
  fvec4 v = ((const fvec4*)s)[j];
  unsigned int lo = (unsigned int)f2bf(v.x) | ((unsigned int)f2bf(v.y) << 16);
  unsigned int hi = (unsigned int)f2bf(v.z) | ((unsigned int)f2bf(v.w) << 16);
  ((uint2*)d)[j] = make_uint2(lo, hi);
}

// ---------------- GEMM: out[m,n] = sum_k A[m,k]*W[n,k] + bias[n] ----------------
// MODE 0: bf16 out.  MODE 1: bf16 out + per-64-col RMSNorm (*rmsScale).  MODE 2: f32 out.
template<int MODE>
__device__ __forceinline__ void gemm_body(
    const ushort* __restrict__ A, const ushort* __restrict__ W,
    const float* __restrict__ bias, ushort* __restrict__ Oh, float* __restrict__ Of,
    const float* __restrict__ nw, float rmsScale,
    int m0, int n0, int N, int K)
{
  __shared__ ushort As[128*64];
  __shared__ ushort Bs[128*64];
  const int tid  = threadIdx.x;
  const int w    = tid >> 6, lid = tid & 63;
  const int lrow = lid & 15, g = lid >> 4;
  const int wm   = (w >> 1) << 6, wn = (w & 1) << 6;

  f32x4 acc[4][4] = {};

  for (int kt = 0; kt < K; kt += 64){
    __syncthreads();
    #pragma unroll
    for (int i = 0; i < 4; ++i){
      int e   = tid + i*256;
      int row = e >> 3;
      int c   = (e & 7) ^ (row & 7);   // pre-swizzle global source (linear LDS dest)
      gload16(A + (size_t)(m0 + row)*K + kt + c*8, &As[e*8]);
      gload16(W + (size_t)(n0 + row)*K + kt + c*8, &Bs[e*8]);
    }
    __syncthreads();
    #pragma unroll
    for (int kc = 0; kc < 2; ++kc){
      bf16x8 af[4], bfr[4];
      #pragma unroll
      for (int r = 0; r < 4; ++r){
        int row = wm + r*16 + lrow;
        af[r] = *(const bf16x8*)&As[row*64 + (((kc*4 + g) ^ (row & 7)) << 3)];
      }
      #pragma unroll
      for (int c = 0; c < 4; ++c){
        int row = wn + c*16 + lrow;
        bfr[c] = *(const bf16x8*)&Bs[row*64 + (((kc*4 + g) ^ (row & 7)) << 3)];
      }
      #pragma unroll
      for (int r = 0; r < 4; ++r)
        #pragma unroll
        for (int c = 0; c < 4; ++c)
          acc[r][c] = __builtin_amdgcn_mfma_f32_16x16x32_bf16(af[r], bfr[c], acc[r][c], 0, 0, 0);
    }
  }
  // epilogue: D row=(lane>>4)*4+b, col=lane&15
  const int colbase = n0 + wn;
  float bv[4], wv4[4];
  #pragma unroll
  for (int c = 0; c < 4; ++c){
    bv[c] = bias[colbase + c*16 + lrow];
    if (MODE == 1) wv4[c] = nw[c*16 + lrow];   // head dim = col % 64 = c*16+lrow
  }
  #pragma unroll
  for (int r = 0; r < 4; ++r){
    #pragma unroll
    for (int b = 0; b < 4; ++b){
      float v[4];
      #pragma unroll
      for (int c = 0; c < 4; ++c) v[c] = acc[r][c][b] + bv[c];
      float sc = 1.0f;
      if (MODE == 1){
        // wave's 64 cols (c,lrow) = exactly one 64-dim head group
        float ss = v[0]*v[0] + v[1]*v[1] + v[2]*v[2] + v[3]*v[3];
        ss += __shfl_xor(ss, 1, 64);
        ss += __shfl_xor(ss, 2, 64);
        ss += __shfl_xor(ss, 4, 64);
        ss += __shfl_xor(ss, 8, 64);
        sc = rsqrtf(ss * (1.0f/64.0f) + 1e-6f) * rmsScale;
      }
      int row = m0 + wm + r*16 + g*4 + b;
      #pragma unroll
      for (int c = 0; c < 4; ++c){
        int col = colbase + c*16 + lrow;
        if (MODE == 2)      Of[(size_t)row*N + col] = v[c];
        else if (MODE == 1) Oh[(size_t)row*N + col] = f2bf(v[c] * sc * wv4[c]);
        else                Oh[(size_t)row*N + col] = f2bf(v[c]);
      }
    }
  }
}

__global__ __launch_bounds__(256) void gemm_qkv(
  const ushort* __restrict__ qbf, const ushort* __restrict__ kvbf,
  const ushort* __restrict__ wq, const ushort* __restrict__ wk, const ushort* __restrict__ wv,
  const float* __restrict__ bq, const float* __restrict__ bk, const float* __restrict__ bv,
  const float* __restrict__ qnw, const float* __restrict__ knw,
  ushort* __restrict__ Q, ushort* __restrict__ Kx, ushort* __restrict__ V)
{
  int bid = blockIdx.x;
  int mt  = bid / 24;
  int ntg = bid % 24;
  int proj = ntg >> 3, nt = ntg & 7;
  // Q gets rmsnorm * (0.125 * log2e)  -> softmax scale folded in; exp2 used directly
  if (proj == 0)
    gemm_body<1>(qbf, wq, bq, Q, nullptr, qnw, 0.18033688011112042f, mt*128, nt*128, Dd, Dd);
  else if (proj == 1)
    gemm_body<1>(kvbf, wk, bk, Kx, nullptr, knw, 1.0f, mt*128, nt*128, Dd, Dd);
  else
    gemm_body<0>(kvbf, wv, bv, V, nullptr, nullptr, 1.0f, mt*128, nt*128, Dd, Dd);
}

__global__ __launch_bounds__(256) void gemm_o(
  const ushort* __restrict__ X, const ushort* __restrict__ wo,
  const float* __restrict__ bo, float* __restrict__ out)
{
  int bid = blockIdx.x;
  int mt = bid / 8, nt = bid % 8;
  gemm_body<2>(X, wo, bo, nullptr, out, nullptr, 1.0f, mt*128, nt*128, Dd, Dd);
}

// ---------------- flash attention, swapped-QK^T, O^T-orientation PV ----------------
// grid = 16 qt * 32 bh (XCD-swizzled); block = 256 = 4 waves; wave owns 32 q (2 subtiles)
// KBLK = 64. 2x-unrolled kt loop with literal buffer index; all LDS addresses hoisted.
__global__ __launch_bounds__(256, 2) void attn_k(
  const ushort* __restrict__ Qb, const ushort* __restrict__ Kb,
  const ushort* __restrict__ Vb, ushort* __restrict__ Ob)
{
  __shared__ ushort lds[4][64*64];   // [0]=Ks buf0, [1]=Ks buf1, [2]=Vt buf0, [3]=Vt buf1

  const int tid = threadIdx.x;
  const int w   = tid >> 6, lid = tid & 63;
  const int r   = lid & 15, g = lid >> 4;

  int bid = blockIdx.x;
  int wg  = (bid & 7) * 64 + (bid >> 3);   // 512 blocks -> 8 XCD contiguous chunks
  int bh  = wg >> 4, qt = wg & 15;
  int bb  = bh >> 4, h = bh & 15;
  const size_t base = (size_t)bb * Tt * Dd + (size_t)h * HDd;

  // Q fragments (B-operand of QK^T)
  bf16x8 qf[2][2];
  #pragma unroll
  for (int sub = 0; sub < 2; ++sub)
    #pragma unroll
    for (int kc = 0; kc < 2; ++kc)
      qf[sub][kc] = *(const bf16x8*)&Qb[base + (size_t)(qt*128 + w*32 + sub*16 + r)*Dd + kc*32 + g*8];

  // ---- hoisted per-thread LDS pointers (buffer 0; buffer 1 = +8192 bytes) ----
  const ushort* kfp[2][4];            // QK^T K-fragment reads
  #pragma unroll
  for (int kc = 0; kc < 2; ++kc)
    #pragma unroll
    for (int t = 0; t < 4; ++t)
      kfp[kc][t] = &lds[0][(t*16 + r)*64 + (((kc*4 + g) ^ (r & 7)) << 3)];

  const ushort* vfp[4][2][2];         // PV V^T-fragment reads
  #pragma unroll
  for (int t16 = 0; t16 < 4; ++t16){
    int d = t16*16 + r, F = ((d >> 3) ^ d) & 7;
    #pragma unroll
    for (int kc = 0; kc < 2; ++kc){
      int c0 = 4*kc + (g >> 1);
      vfp[t16][kc][0] = &lds[2][d*64 + 4*(g & 1) + (((c0    ) ^ F) << 3)];
      vfp[t16][kc][1] = &lds[2][d*64 + 4*(g & 1) + (((c0 + 2) ^ F) << 3)];
    }
  }

  ushort* sca0[8]; ushort* sca1[8];   // V^T scatter writes
  #pragma unroll
  for (int i = 0; i < 2; ++i){
    int e = tid + i*256, kr = e >> 3, c8 = (e & 7) << 3;
    #pragma unroll
    for (int j = 0; j < 8; ++j){
      int d = c8 + j, F = ((d >> 3) ^ d) & 7;
      ushort* pp = &lds[2][d*64 + (((kr >> 3) ^ F) << 3) + (kr & 7)];
      if (i == 0) sca0[j] = pp; else sca1[j] = pp;
    }
  }

  ushort* kdst0 = &lds[0][tid*8];
  ushort* kdst1 = &lds[0][(tid + 256)*8];

  // ---- global staging pointers (running) ----
  const ushort *ks0g, *ks1g, *vs0g, *vs1g;
  {
    int e0 = tid, e1 = tid + 256;
    int r0 = e0 >> 3, c0 = (e0 & 7) ^ (r0 & 7);
    int r1 = e1 >> 3, c1 = (e1 & 7) ^ (r1 & 7);
    ks0g = Kb + base + (size_t)r0 * Dd + c0*8;
    ks1g = Kb + base + (size_t)r1 * Dd + c1*8;
    vs0g = Vb + base + (size_t)(e0 >> 3) * Dd + (e0 & 7)*8;
    vs1g = Vb + base + (size_t)(e1 >> 3) * Dd + (e1 & 7)*8;
  }
  const size_t kstep = (size_t)64 * Dd;

  // prologue: tile 0 -> buffer 0
  gload16(ks0g, kdst0);
  gload16(ks1g, kdst1);
  s16x8 vr0 = *(const s16x8*)vs0g;
  s16x8 vr1 = *(const s16x8*)vs1g;
  ks0g += kstep; ks1g += kstep; vs0g += kstep; vs1g += kstep;

  f32x4 o[2][4] = {};          // o[sub][t16]: O[q=r][d = t16*16 + g*4 + b]
  float mr0 = -1e30f, mr1 = -1e30f;
  float lr0 = 0.f,    lr1 = 0.f;

  // online softmax + defer-max + cvt_pk P-pack (q = r is lane-local)
  auto dosm = [&](const f32x4* s, float& m, float& l, f32x4* oo, bf16x8* pao){
    float t0 = fmaxf(fmaxf(s[0][0], s[0][1]), s[0][2]);
    float t1 = fmaxf(fmaxf(s[0][3], s[1][0]), s[1][1]);
    float t2 = fmaxf(fmaxf(s[1][2], s[1][3]), s[2][0]);
    float t3 = fmaxf(fmaxf(s[2][1], s[2][2]), s[2][3]);
    float t4 = fmaxf(fmaxf(s[3][0], s[3][1]), s[3][2]);
    float mx = fmaxf(fmaxf(fmaxf(t0, t1), fmaxf(t2, t3)), fmaxf(t4, s[3][3]));
    mx = fmaxf(mx, __shfl_xor(mx, 16, 64));
    mx = fmaxf(mx, __shfl_xor(mx, 32, 64));
    const bool defer = (__all(mx - m <= 8.0f) != 0);   // wave-uniform branch
    float nm = defer ? m : fmaxf(m, mx);
    float p[4][4]; float rs = 0.f;
    #pragma unroll
    for (int t = 0; t < 4; ++t)
      #pragma unroll
      for (int b = 0; b < 4; ++b){
        float e = __builtin_amdgcn_exp2f(s[t][b] - nm);   // scale pre-folded (log2 domain)
        p[t][b] = e; rs += e;
      }
    rs += __shfl_xor(rs, 16, 64);
    rs += __shfl_xor(rs, 32, 64);
    if (defer){
      l += rs;
    } else {
      float f = __builtin_amdgcn_exp2f(m - nm);
      l = l * f + rs; m = nm;
      #pragma unroll
      for (int t16 = 0; t16 < 4; ++t16) oo[t16] *= f;
    }
    // pack P as PV B-operand: slot j of pao[kc] = p[(j>>2)+2kc][j&3]
    #pragma unroll
    for (int kc = 0; kc < 2; ++kc){
      unsigned u0, u1, u2, u3;
      asm("v_cvt_pk_bf16_f32 %0, %1, %2" : "=v"(u0) : "v"(p[2*kc  ][0]), "v"(p[2*kc  ][1]));
      asm("v_cvt_pk_bf16_f32 %0, %1, %2" : "=v"(u1) : "v"(p[2*kc  ][2]), "v"(p[2*kc  ][3]));
      asm("v_cvt_pk_bf16_f32 %0, %1, %2" : "=v"(u2) : "v"(p[2*kc+1][0]), "v"(p[2*kc+1][1]));
      asm("v_cvt_pk_bf16_f32 %0, %1, %2" : "=v"(u3) : "v"(p[2*kc+1][2]), "v"(p[2*kc+1][3]));
      u32x4 uu = {u0, u1, u2, u3};
      pao[kc] = __builtin_bit_cast(bf16x8, uu);
    }
  };

#define ATTN_TILE(BUF, PREFETCH)                                                     \
  {                                                                                  \
    _Pragma("unroll")                                                                \
    for (int j = 0; j < 8; ++j){                                                     \
      *(ushort*)((char*)sca0[j] + (BUF)*8192) = (ushort)vr0[j];                      \
      *(ushort*)((char*)sca1[j] + (BUF)*8192) = (ushort)vr1[j];                      \
    }                                                                                \
    __syncthreads();                                                                 \
    if (PREFETCH){                                                                   \
      gload16(ks0g, (char*)kdst0 + ((BUF)^1)*8192);                                  \
      gload16(ks1g, (char*)kdst1 + ((BUF)^1)*8192);                                  \
      vr0 = *(const s16x8*)vs0g;                                                     \
      vr1 = *(const s16x8*)vs1g;                                                     \
      ks0g += kstep; ks1g += kstep; vs0g += kstep; vs1g += kstep;                    \
    }                                                                                \
    f32x4 s0[4] = {}, s1[4] = {};                                                    \
    __builtin_amdgcn_s_setprio(1);                                                   \
    _Pragma("unroll")                                                                \
    for (int kc = 0; kc < 2; ++kc)                                                   \
      _Pragma("unroll")                                                              \
      for (int t = 0; t < 4; ++t){                                                   \
        bf16x8 kf = *(const bf16x8*)((const char*)kfp[kc][t] + (BUF)*8192);          \
        s0[t] = __builtin_amdgcn_mfma_f32_16x16x32_bf16(kf, qf[0][kc], s0[t], 0,0,0);\
        s1[t] = __builtin_amdgcn_mfma_f32_16x16x32_bf16(kf, qf[1][kc], s1[t], 0,0,0);\
      }                                                                              \
    __builtin_amdgcn_s_setprio(0);                                                   \
    bf16x8 pa0[2], pa1[2];                                                           \
    dosm(s0, mr0, lr0, o[0], pa0);                                                   \
    dosm(s1, mr1, lr1, o[1], pa1);                                                   \
    __builtin_amdgcn_s_setprio(1);                                                   \
    _Pragma("unroll")                                                                \
    for (int t16 = 0; t16 < 4; ++t16){                                               \
      _Pragma("unroll")                                                              \
      for (int kc = 0; kc < 2; ++kc){                                                \
        s16x4 a0 = *(const s16x4*)((const char*)vfp[t16][kc][0] + (BUF)*8192);       \
        s16x4 a1 = *(const s16x4*)((const char*)vfp[t16][kc][1] + (BUF)*8192);       \
        bf16x8 vf = cat4(a0, a1);                                                    \
        o[0][t16] = __builtin_amdgcn_mfma_f32_16x16x32_bf16(vf, pa0[kc], o[0][t16], 0,0,0); \
        o[1][t16] = __builtin_amdgcn_mfma_f32_16x16x32_bf16(vf, pa1[kc], o[1][t16], 0,0,0); \
      }                                                                              \
    }                                                                                \
    __builtin_amdgcn_s_setprio(0);                                                   \
  }

  for (int kt2 = 0; kt2 < 16; ++kt2){
    ATTN_TILE(0, true);
    ATTN_TILE(1, (kt2 != 15));
  }
#undef ATTN_TILE

  // ---- finalize: O /= l (lane-local), write 4 contiguous bf16 (8B) per t16
  #pragma unroll
  for (int sub = 0; sub < 2; ++sub){
    float inv = 1.0f / (sub ? lr1 : lr0);
    int qrow = qt*128 + w*32 + sub*16 + r;
    #pragma unroll
    for (int t16 = 0; t16 < 4; ++t16){
      uint2 u;
      u.x = (unsigned)f2bf(o[sub][t16][0]*inv) | ((unsigned)f2bf(o[sub][t16][1]*inv) << 16);
      u.y = (unsigned)f2bf(o[sub][t16][2]*inv) | ((unsigned)f2bf(o[sub][t16][3]*inv) << 16);
      *(uint2*)&Ob[base + (size_t)qrow*Dd + t16*16 + g*4] = u;
    }
  }
}

extern "C" void kernel_launch(void* const* d_in, const int* in_sizes, int n_in,
                              void* d_out, int out_size, void* d_ws, size_t ws_size,
                              hipStream_t stream)
{
  const float* query = (const float*)d_in[0];
  const float* keyv  = (const float*)d_in[1];
  const float* Wq    = (const float*)d_in[2];
  const float* bq    = (const float*)d_in[3];
  const float* Wk    = (const float*)d_in[4];
  const float* bk    = (const float*)d_in[5];
  const float* Wv    = (const float*)d_in[6];
  const float* bv    = (const float*)d_in[7];
  const float* Wo    = (const float*)d_in[8];
  const float* bo    = (const float*)d_in[9];
  const float* qnw   = (const float*)d_in[10];
  const float* knw   = (const float*)d_in[11];
  float* out = (float*)d_out;

  char* p = (char*)d_ws;
  ushort* qbf  = (ushort*)p; p += (size_t)Mm*Dd*2;
  ushort* kvbf = (ushort*)p; p += (size_t)Mm*Dd*2;
  ushort* wqb  = (ushort*)p; p += (size_t)Dd*Dd*2;
  ushort* wkb  = (ushort*)p; p += (size_t)Dd*Dd*2;
  ushort* wvb  = (ushort*)p; p += (size_t)Dd*Dd*2;
  ushort* wob  = (ushort*)p; p += (size_t)Dd*Dd*2;
  ushort* Qb   = (ushort*)p; p += (size_t)Mm*Dd*2;
  ushort* Kbf  = (ushort*)p; p += (size_t)Mm*Dd*2;
  ushort* Vbf  = (ushort*)p; p += (size_t)Mm*Dd*2;
  ushort* Ab   = (ushort*)p; p += (size_t)Mm*Dd*2;

  cvt_all<<<dim3(12288), dim3(256), 0, stream>>>(query, keyv, Wq, Wk, Wv, Wo,
                                                 qbf, kvbf, wqb, wkb, wvb, wob);

  gemm_qkv<<<dim3(768), dim3(256), 0, stream>>>(qbf, kvbf, wqb, wkb, wvb,
                                                bq, bk, bv, qnw, knw, Qb, Kbf, Vbf);

  attn_k<<<dim3(512), dim3(256), 0, stream>>>(Qb, Kbf, Vbf, Ab);

  gemm_o<<<dim3(256), dim3(256), 0, stream>>>(Ab, wob, bo, out);
}